// Round 3
// baseline (928.430 us; speedup 1.0000x reference)
//
#include <hip/hip_runtime.h>
#include <stdint.h>

// ---------------------------------------------------------------------------
// ResidueGraphModel: aanet_proj (512->1024->1024->512->80, ReLU) -> in_net
// (80->512) -> GIN sum-aggregation + MLP (512->512->512) -> out_net (512->80).
// bf16 MFMA GEMMs (fp32 accumulate), 128x128 tiles, BK=64.
// R3: 32x32x16 MFMA (2x FLOP per LDS-read/VALU, +15% MFMA ceiling), merged
// weight-transpose launch. Kept from R2: XOR-swizzled LDS (0 bank conflicts),
// operand-swapped MFMA (packed 8B C stores), XCD-grouped block decode,
// aggregation before in_net (80-dim gather, deg-scaled bias).
// Outputs fp32: d_out = [peptide_mask (N*80) | peptide_feat (N*80)].
// ---------------------------------------------------------------------------

using bf16x8 = __attribute__((ext_vector_type(8))) short;
using f32x16 = __attribute__((ext_vector_type(16))) float;

__device__ inline unsigned short f2bf(float f) {
    union { float f; unsigned u; } v; v.f = f;
    unsigned u = v.u;
    u += 0x7FFFu + ((u >> 16) & 1u);   // RNE
    return (unsigned short)(u >> 16);
}
__device__ inline float bf2f(unsigned u16) {
    return __uint_as_float(u16 << 16);
}

// ------------- merged weight transpose: W[K][M] f32 -> Wt[Mp][Kp] bf16 ------
struct TDescs {
    const float* W[8]; unsigned short* Wt[8];
    int K[8], M[8], Kp[8], ntx[8], start[8];
};

__global__ void rg_transpose_all(TDescs d) {
    __shared__ float t[32][33];
    int b = blockIdx.x;
    int di = 0;
#pragma unroll
    for (int i = 1; i < 8; ++i) if (b >= d.start[i]) di = i;
    int local = b - d.start[di];
    int bx = local % d.ntx[di];
    int by = local / d.ntx[di];
    const float* W = d.W[di];
    unsigned short* Wt = d.Wt[di];
    int K = d.K[di], M = d.M[di], Kp = d.Kp[di];

    int mb = bx * 32, kb = by * 32;
    int tx = threadIdx.x, ty = threadIdx.y;
    int k = kb + ty, m = mb + tx;
    float v = (k < K && m < M) ? W[(size_t)k * M + m] : 0.f;
    t[ty][tx] = v;
    __syncthreads();
    int mo = mb + ty, ko = kb + tx;
    Wt[(size_t)mo * Kp + ko] = f2bf(t[tx][ty]);
}

// ---------------- f32 -> bf16 elementwise (4 per thread) --------------------
__global__ void rg_f32_to_bf16(const float* __restrict__ in, unsigned short* __restrict__ out, int n) {
    int i = (blockIdx.x * 256 + threadIdx.x) * 4;
    if (i + 3 < n) {
        float4 v = *(const float4*)(in + i);
        ushort4 o; o.x = f2bf(v.x); o.y = f2bf(v.y); o.z = f2bf(v.z); o.w = f2bf(v.w);
        *(ushort4*)(out + i) = o;
    }
}

// ---------------- GEMM: C[N,Mp] = act(A[N,Kp] @ Wt[Mp,Kp]^T + bscale*bias) --
// 32x32x16 MFMA. XOR swizzle: LDS chunk q (16B) of tile row r holds global
// chunk (q&7)^(r&7); fragment reads apply the same XOR. Operand swap:
// weights first -> acc reg groups of 4 = 4 consecutive output columns.
template <bool RELU, bool OUT_BF, bool OUT_F32, bool DEGB>
__global__ __launch_bounds__(256) void rg_gemm(
    const unsigned short* __restrict__ A, const unsigned short* __restrict__ Bt,
    const float* __restrict__ bias, const int* __restrict__ deg, int Mvalid,
    unsigned short* __restrict__ outB, float* __restrict__ outF,
    int Nrows, int Kp, int Mp, int gN, int MT)
{
    __shared__ __align__(16) unsigned short As[128 * 64];
    __shared__ __align__(16) unsigned short Bs[128 * 64];

    // XCD-grouped decode: a row strip's MT col-blocks share (bid&7), 8 apart
    // in issue order -> A strip stays hot in L2/L3 across column passes.
    int bid = blockIdx.x;
    int xcd = bid & 7;
    int slot = bid >> 3;
    int c = slot % MT;
    int rsub = slot / MT;
    int rt = rsub * 8 + xcd;
    if (rt >= gN) return;
    const int rowBase = rt * 128;
    const int nBase   = c * 128;

    const int tid  = threadIdx.x;
    const int lane = tid & 63;
    const int half = lane >> 5;
    const int lrow = lane & 31;
    const int w    = tid >> 6;
    const int wm   = w & 1, wn = w >> 1;

    f32x16 acc[2][2];
#pragma unroll
    for (int i = 0; i < 2; ++i)
#pragma unroll
        for (int j = 0; j < 2; ++j)
#pragma unroll
            for (int e = 0; e < 16; ++e) acc[i][j][e] = 0.f;

    const int nkt = Kp >> 6;
    for (int kt = 0; kt < nkt; ++kt) {
        __syncthreads();
        const int k0 = kt * 64;
#pragma unroll
        for (int i = 0; i < 4; ++i) {
            int q   = i * 256 + tid;       // LDS 16B-chunk slot
            int r   = q >> 3;
            int cbg = (q & 7) ^ (r & 7);   // global chunk staged into slot q
            int gr  = rowBase + r; if (gr >= Nrows) gr = Nrows - 1;
            const unsigned short* gp = A + (size_t)gr * Kp + k0 + cbg * 8;
            __builtin_amdgcn_global_load_lds(
                (const __attribute__((address_space(1))) void*)gp,
                (__attribute__((address_space(3))) void*)(&As[q * 8]), 16, 0, 0);
        }
#pragma unroll
        for (int i = 0; i < 4; ++i) {
            int q   = i * 256 + tid;
            int r   = q >> 3;
            int cbg = (q & 7) ^ (r & 7);
            const unsigned short* gp = Bt + (size_t)(nBase + r) * Kp + k0 + cbg * 8;
            __builtin_amdgcn_global_load_lds(
                (const __attribute__((address_space(1))) void*)gp,
                (__attribute__((address_space(3))) void*)(&Bs[q * 8]), 16, 0, 0);
        }
        __syncthreads();
#pragma unroll
        for (int ks = 0; ks < 4; ++ks) {
            const int cb = ks * 2 + half;   // 16B k-chunk index within row
            bf16x8 a[2], b[2];
#pragma unroll
            for (int i = 0; i < 2; ++i) {
                int r = wm * 64 + i * 32 + lrow;
                a[i] = *(const bf16x8*)&As[(r * 8 + (cb ^ (r & 7))) * 8];
            }
#pragma unroll
            for (int j = 0; j < 2; ++j) {
                int r = wn * 64 + j * 32 + lrow;
                b[j] = *(const bf16x8*)&Bs[(r * 8 + (cb ^ (r & 7))) * 8];
            }
#pragma unroll
            for (int i = 0; i < 2; ++i)
#pragma unroll
                for (int j = 0; j < 2; ++j)
                    // swapped: weights first -> D cols from regs, rows from lane
                    acc[i][j] = __builtin_amdgcn_mfma_f32_32x32x16_bf16(b[j], a[i], acc[i][j], 0, 0, 0);
        }
    }

    // epilogue: out_row = lane&31 (+32i+64wm); out_col = 8*(reg>>2)+4*half+(reg&3)
#pragma unroll
    for (int i = 0; i < 2; ++i) {
        int row = rowBase + wm * 64 + i * 32 + lrow;
        if (row >= Nrows) continue;
        float sc = 1.f;
        if (DEGB) sc = 1.f + (float)deg[row];
#pragma unroll
        for (int j = 0; j < 2; ++j) {
#pragma unroll
            for (int g = 0; g < 4; ++g) {
                int colb = nBase + wn * 64 + j * 32 + g * 8 + half * 4;
                float4 bv = (colb < Mvalid) ? *(const float4*)(bias + colb)
                                            : (float4){0.f, 0.f, 0.f, 0.f};
                float v0 = acc[i][j][g * 4 + 0] + sc * bv.x;
                float v1 = acc[i][j][g * 4 + 1] + sc * bv.y;
                float v2 = acc[i][j][g * 4 + 2] + sc * bv.z;
                float v3 = acc[i][j][g * 4 + 3] + sc * bv.w;
                if (RELU) {
                    v0 = v0 > 0.f ? v0 : 0.f; v1 = v1 > 0.f ? v1 : 0.f;
                    v2 = v2 > 0.f ? v2 : 0.f; v3 = v3 > 0.f ? v3 : 0.f;
                }
                if (OUT_BF) {
                    ushort4 o; o.x = f2bf(v0); o.y = f2bf(v1); o.z = f2bf(v2); o.w = f2bf(v3);
                    *(ushort4*)(outB + (size_t)row * Mp + colb) = o;
                }
                if (OUT_F32) {
                    if (colb < Mvalid)
                        *(float4*)(outF + (size_t)row * Mvalid + colb) = (float4){v0, v1, v2, v3};
                }
            }
        }
    }
}

// ---------------- CSR build ------------------------------------------------
__global__ void rg_count_edges(const int* __restrict__ ei, int E, int* __restrict__ cnt) {
    int e = blockIdx.x * 256 + threadIdx.x;
    if (e < E) atomicAdd(&cnt[ei[E + e]], 1);
}

__global__ void rg_scan_block(const int* __restrict__ cnt, int* __restrict__ scanned,
                              int* __restrict__ bsums, int Nn) {
    __shared__ int sd[1024];
    int tid = threadIdx.x;
    int i = blockIdx.x * 1024 + tid;
    int v = (i < Nn) ? cnt[i] : 0;
    sd[tid] = v;
    __syncthreads();
    for (int off = 1; off < 1024; off <<= 1) {
        int t = (tid >= off) ? sd[tid - off] : 0;
        __syncthreads();
        sd[tid] += t;
        __syncthreads();
    }
    if (i < Nn) scanned[i] = sd[tid];
    if (tid == 1023) bsums[blockIdx.x] = sd[1023];
}

__global__ void rg_scan_sums(int* __restrict__ b, int nb) {
    if (threadIdx.x == 0) {
        int acc = 0;
        for (int i = 0; i < nb; ++i) { int t = b[i]; b[i] = acc; acc += t; }
    }
}

__global__ void rg_scan_add(const int* __restrict__ scanned, const int* __restrict__ bsums,
                            const int* __restrict__ cnt, int* __restrict__ rowptr,
                            int* __restrict__ cursor, int Nn, int E) {
    int i = blockIdx.x * 1024 + threadIdx.x;
    if (i < Nn) {
        int ex = scanned[i] - cnt[i] + bsums[blockIdx.x];
        rowptr[i] = ex; cursor[i] = ex;
    }
    if (i == 0) rowptr[Nn] = E;
}

__global__ void rg_scatter_edges(const int* __restrict__ ei, int E,
                                 int* __restrict__ cursor, int* __restrict__ cols) {
    int e = blockIdx.x * 256 + threadIdx.x;
    if (e < E) {
        int d = ei[E + e];
        int p = atomicAdd(&cursor[d], 1);
        cols[p] = ei[e];
    }
}

// ---------------- 80-dim aggregation: s[i] = pf[i] + sum_{src->i} pf[src] --
// pf is [N,128] bf16 (padded). One wave per node, 2 cols/lane (4B loads).
__global__ __launch_bounds__(256) void rg_agg80(
    const unsigned short* __restrict__ pf, const int* __restrict__ rowptr,
    const int* __restrict__ cols, unsigned short* __restrict__ s, int Nn)
{
    int node = blockIdx.x * 4 + (threadIdx.x >> 6);
    if (node >= Nn) return;
    int lane = threadIdx.x & 63;
    const unsigned* xp = (const unsigned*)pf;   // 64 uints per row
    size_t off = (size_t)node * 64 + lane;
    unsigned u = xp[off];
    float a0 = bf2f(u & 0xffffu), a1 = bf2f(u >> 16);
    int beg = rowptr[node], end = rowptr[node + 1];
    for (int e = beg; e < end; ++e) {
        int src = cols[e];
        unsigned v = xp[(size_t)src * 64 + lane];
        a0 += bf2f(v & 0xffffu); a1 += bf2f(v >> 16);
    }
    unsigned o = (unsigned)f2bf(a0) | ((unsigned)f2bf(a1) << 16);
    ((unsigned*)s)[off] = o;
}

// ---------------------------------------------------------------------------
extern "C" void kernel_launch(void* const* d_in, const int* in_sizes, int n_in,
                              void* d_out, int out_size, void* d_ws, size_t ws_size,
                              hipStream_t stream)
{
    const float* feat = (const float*)d_in[0];
    const int*   ei   = (const int*)d_in[1];
    const float* W1 = (const float*)d_in[2];  const float* b1 = (const float*)d_in[3];
    const float* W2 = (const float*)d_in[4];  const float* b2 = (const float*)d_in[5];
    const float* W3 = (const float*)d_in[6];  const float* b3 = (const float*)d_in[7];
    const float* W4 = (const float*)d_in[8];  const float* b4 = (const float*)d_in[9];
    const float* Wi = (const float*)d_in[10]; const float* bi = (const float*)d_in[11];
    const float* Wg1 = (const float*)d_in[12]; const float* bg1 = (const float*)d_in[13];
    const float* Wg2 = (const float*)d_in[14]; const float* bg2 = (const float*)d_in[15];
    const float* Wo = (const float*)d_in[16]; const float* bo = (const float*)d_in[17];

    const int N = in_sizes[0] / 512;   // 50000
    const int E = in_sizes[1] / 2;     // 800000

    char* ws = (char*)d_ws;
    size_t o = 0;
    auto alloc = [&](size_t bytes) { char* p = ws + o; o += (bytes + 255) & ~(size_t)255; return p; };
    unsigned short* bufA = (unsigned short*)alloc((size_t)N * 1024 * 2); // h1 / pf / g
    unsigned short* bufB = (unsigned short*)alloc((size_t)N * 1024 * 2); // h2 / r1
    unsigned short* bufC = (unsigned short*)alloc((size_t)N * 512 * 2);  // A0 / h3 / s / g2
    unsigned short* W1t = (unsigned short*)alloc((size_t)1024 * 512 * 2);
    unsigned short* W2t = (unsigned short*)alloc((size_t)1024 * 1024 * 2);
    unsigned short* W3t = (unsigned short*)alloc((size_t)512 * 1024 * 2);
    unsigned short* W4t = (unsigned short*)alloc((size_t)128 * 512 * 2);
    unsigned short* Wit = (unsigned short*)alloc((size_t)512 * 128 * 2);
    unsigned short* Wg1t = (unsigned short*)alloc((size_t)512 * 512 * 2);
    unsigned short* Wg2t = (unsigned short*)alloc((size_t)512 * 512 * 2);
    unsigned short* Wot = (unsigned short*)alloc((size_t)128 * 512 * 2);
    int* cnt    = (int*)alloc((size_t)N * 4);
    int* rowptr = (int*)alloc((size_t)(N + 1) * 4);
    int* cursor = (int*)alloc((size_t)N * 4);
    int* cols   = (int*)alloc((size_t)E * 4);   // reused as `scanned` pre-scatter
    int* bsums  = (int*)alloc(256);

    float* out_mask = (float*)d_out;                  // [N,80]
    float* out_feat = (float*)d_out + (size_t)N * 80; // [N,80]

    // ---- CSR build (independent of GEMM chain) ----
    int* scanned = cols;  // consumed by rg_scan_add before rg_scatter writes cols
    hipMemsetAsync(cnt, 0, (size_t)N * 4, stream);
    rg_count_edges<<<(E + 255) / 256, 256, 0, stream>>>(ei, E, cnt);
    const int nb = (N + 1023) / 1024;
    rg_scan_block<<<nb, 1024, 0, stream>>>(cnt, scanned, bsums, N);
    rg_scan_sums<<<1, 64, 0, stream>>>(bsums, nb);
    rg_scan_add<<<nb, 1024, 0, stream>>>(scanned, bsums, cnt, rowptr, cursor, N, E);
    rg_scatter_edges<<<(E + 255) / 256, 256, 0, stream>>>(ei, E, cursor, cols);

    // ---- weight prep: one merged launch ----
    {
        TDescs d;
        const float* Ws[8]  = {W1, W2, W3, W4, Wi, Wg1, Wg2, Wo};
        unsigned short* Ts[8] = {W1t, W2t, W3t, W4t, Wit, Wg1t, Wg2t, Wot};
        int Ks[8]  = {512, 1024, 1024, 512, 80, 512, 512, 512};
        int Ms[8]  = {1024, 1024, 512, 80, 512, 512, 512, 80};
        int Kps[8] = {512, 1024, 1024, 512, 128, 512, 512, 512};
        int Mps[8] = {1024, 1024, 512, 128, 512, 512, 512, 128};
        int st = 0;
        for (int i = 0; i < 8; ++i) {
            d.W[i] = Ws[i]; d.Wt[i] = Ts[i];
            d.K[i] = Ks[i]; d.M[i] = Ms[i]; d.Kp[i] = Kps[i];
            d.ntx[i] = Mps[i] / 32;
            d.start[i] = st;
            st += (Mps[i] / 32) * (Kps[i] / 32);
        }
        rg_transpose_all<<<st, dim3(32, 32), 0, stream>>>(d);
    }

    rg_f32_to_bf16<<<(N * 512) / 1024, 256, 0, stream>>>(feat, bufC, N * 512);

    const int gN = (N + 127) / 128;          // 391
    const int rg8 = ((gN + 7) / 8) * 8;      // 392
    auto grid = [&](int MT) { return dim3(rg8 * MT); };

    // L1: h1 = relu(A0 @ W1 + b1)   [N,1024]
    rg_gemm<true, true, false, false><<<grid(8), 256, 0, stream>>>(bufC, W1t, b1, nullptr, 1024, bufA, nullptr, N, 512, 1024, gN, 8);
    // L2: h2 = relu(h1 @ W2 + b2)   [N,1024]
    rg_gemm<true, true, false, false><<<grid(8), 256, 0, stream>>>(bufA, W2t, b2, nullptr, 1024, bufB, nullptr, N, 1024, 1024, gN, 8);
    // L3: h3 = relu(h2 @ W3 + b3)   [N,512]
    rg_gemm<true, true, false, false><<<grid(4), 256, 0, stream>>>(bufB, W3t, b3, nullptr, 512, bufC, nullptr, N, 1024, 512, gN, 4);
    // L4: pf = h3 @ W4 + b4  -> fp32 out_feat + bf16 padded [N,128]
    rg_gemm<false, true, true, false><<<grid(1), 256, 0, stream>>>(bufC, W4t, b4, nullptr, 80, bufA, out_feat, N, 512, 128, gN, 1);

    // 80-dim aggregation: s = pf + segsum(pf[src]) -> bufC[:, :128]
    rg_agg80<<<(N + 3) / 4, 256, 0, stream>>>(bufA, rowptr, cols, bufC, N);

    // L5: g = s @ Win + (1+deg)*bin  [N,512]   (agg moved before affine in_net)
    rg_gemm<false, true, false, true><<<grid(4), 256, 0, stream>>>(bufC, Wit, bi, cnt, 512, bufA, nullptr, N, 128, 512, gN, 4);
    // L6: r1 = relu(g @ Wg1 + bg1)  [N,512]
    rg_gemm<true, true, false, false><<<grid(4), 256, 0, stream>>>(bufA, Wg1t, bg1, nullptr, 512, bufB, nullptr, N, 512, 512, gN, 4);
    // L7: g2 = r1 @ Wg2 + bg2       [N,512]
    rg_gemm<false, true, false, false><<<grid(4), 256, 0, stream>>>(bufB, Wg2t, bg2, nullptr, 512, bufC, nullptr, N, 512, 512, gN, 4);
    // L8: mask = g2 @ Wout + bout -> fp32 out_mask
    rg_gemm<false, false, true, false><<<grid(1), 256, 0, stream>>>(bufC, Wot, bo, nullptr, 80, nullptr, out_mask, N, 512, 128, gN, 1);
}

// Round 4
// 846.547 us; speedup vs baseline: 1.0967x; 1.0967x over previous
//
#include <hip/hip_runtime.h>
#include <stdint.h>

// ---------------------------------------------------------------------------
// ResidueGraphModel: aanet_proj (512->1024->1024->512->80, ReLU) -> in_net
// (80->512) -> GIN sum-aggregation + MLP (512->512->512) -> out_net (512->80).
// bf16 MFMA GEMMs (fp32 accumulate), 128x128 tiles, BK=64, 16x16x32 MFMA.
// R4: revert to R2's GEMM (R3's 32x32x16 brought back bank conflicts +
// write amplification: 1.28e7 conflict cycles + 170 MB writes for 102 MB
// output). Kept: XOR-swizzled LDS (0 conflicts), operand-swapped MFMA
// (packed 8B C stores, 32B/row per instruction), XCD-grouped block decode,
// aggregation before in_net. New: single merged preprocessing launch
// (8 transposes + f32->bf16 convert + edge count).
// Outputs fp32: d_out = [peptide_mask (N*80) | peptide_feat (N*80)].
// ---------------------------------------------------------------------------

using bf16x8 = __attribute__((ext_vector_type(8))) short;
using f32x4  = __attribute__((ext_vector_type(4))) float;

__device__ inline unsigned short f2bf(float f) {
    union { float f; unsigned u; } v; v.f = f;
    unsigned u = v.u;
    u += 0x7FFFu + ((u >> 16) & 1u);   // RNE
    return (unsigned short)(u >> 16);
}
__device__ inline float bf2f(unsigned u16) {
    return __uint_as_float(u16 << 16);
}

// ------------- merged preprocessing ----------------------------------------
// Block ranges: [0, tEnd) -> weight transpose+convert (32x32 tiles, 256 thr)
//               [tEnd, cEnd) -> feat f32->bf16 convert (1024 elems/block)
//               [cEnd, eEnd) -> edge dst counting (256 edges/block)
struct PreDescs {
    const float* W[8]; unsigned short* Wt[8];
    int K[8], M[8], Kp[8], ntx[8], start[8];
    int tEnd, cEnd, eEnd;
    const float* feat; unsigned short* featb; int nFeat;
    const int* ei; int E; int* cnt;
};

__global__ __launch_bounds__(256) void rg_preprocess(PreDescs d) {
    int b = blockIdx.x;
    int tid = threadIdx.x;
    if (b < d.tEnd) {
        // transpose: W[K][M] f32 -> Wt[Mp][Kp] bf16 (pad with 0)
        __shared__ float t[32][33];
        int di = 0;
#pragma unroll
        for (int i = 1; i < 8; ++i) if (b >= d.start[i]) di = i;
        int local = b - d.start[di];
        int bx = local % d.ntx[di];
        int by = local / d.ntx[di];
        const float* W = d.W[di];
        unsigned short* Wt = d.Wt[di];
        int K = d.K[di], M = d.M[di], Kp = d.Kp[di];
        int mb = bx * 32, kb = by * 32;
        int tx = tid & 31, tg = tid >> 5;   // 8 rows per pass, 4 passes
#pragma unroll
        for (int p = 0; p < 4; ++p) {
            int r = tg + p * 8;             // tile row (k-dir)
            int k = kb + r, m = mb + tx;
            t[r][tx] = (k < K && m < M) ? W[(size_t)k * M + m] : 0.f;
        }
        __syncthreads();
#pragma unroll
        for (int p = 0; p < 4; ++p) {
            int r = tg + p * 8;             // tile row (m-dir)
            int mo = mb + r, ko = kb + tx;
            Wt[(size_t)mo * Kp + ko] = f2bf(t[tx][r]);
        }
    } else if (b < d.cEnd) {
        int i = ((b - d.tEnd) * 256 + tid) * 4;
        if (i + 3 < d.nFeat) {
            float4 v = *(const float4*)(d.feat + i);
            ushort4 o; o.x = f2bf(v.x); o.y = f2bf(v.y); o.z = f2bf(v.z); o.w = f2bf(v.w);
            *(ushort4*)(d.featb + i) = o;
        }
    } else {
        int e = (b - d.cEnd) * 256 + tid;
        if (e < d.E) atomicAdd(&d.cnt[d.ei[d.E + e]], 1);
    }
}

// ---------------- GEMM: C[N,Mp] = act(A[N,Kp] @ Wt[Mp,Kp]^T + bscale*bias) --
// XOR swizzle: LDS chunk q (16B) of a tile row r holds global chunk
// (q&7)^(r&7); staging lane loads the matching global address, fragment
// reads apply the same XOR -> zero measured bank conflicts.
// Operand swap: weights as first MFMA operand -> acc regs hold 4 consecutive
// output columns -> 8B packed stores (32B/row per store instruction).
template <bool RELU, bool OUT_BF, bool OUT_F32, bool DEGB>
__global__ __launch_bounds__(256) void rg_gemm(
    const unsigned short* __restrict__ A, const unsigned short* __restrict__ Bt,
    const float* __restrict__ bias, const int* __restrict__ deg, int Mvalid,
    unsigned short* __restrict__ outB, float* __restrict__ outF,
    int Nrows, int Kp, int Mp, int gN, int MT)
{
    __shared__ __align__(16) unsigned short As[128 * 64];
    __shared__ __align__(16) unsigned short Bs[128 * 64];

    // XCD-grouped decode: a row strip's MT col-blocks share (bid&7), 8 apart
    // in issue order -> A strip stays hot in L2/L3 across column passes.
    int bid = blockIdx.x;
    int xcd = bid & 7;
    int slot = bid >> 3;
    int c = slot % MT;
    int rsub = slot / MT;
    int rt = rsub * 8 + xcd;
    if (rt >= gN) return;
    const int rowBase = rt * 128;
    const int nBase   = c * 128;

    const int tid  = threadIdx.x;
    const int lane = tid & 63;
    const int w    = tid >> 6;
    const int wm   = w & 1, wn = w >> 1;

    f32x4 acc[4][4];
#pragma unroll
    for (int i = 0; i < 4; ++i)
#pragma unroll
        for (int j = 0; j < 4; ++j) acc[i][j] = (f32x4){0.f, 0.f, 0.f, 0.f};

    const int nkt = Kp >> 6;
    for (int kt = 0; kt < nkt; ++kt) {
        __syncthreads();
        const int k0 = kt * 64;
#pragma unroll
        for (int i = 0; i < 4; ++i) {
            int q   = i * 256 + tid;       // LDS 16B-chunk slot
            int r   = q >> 3;
            int cbg = (q & 7) ^ (r & 7);   // global chunk staged into slot q
            int gr  = rowBase + r; if (gr >= Nrows) gr = Nrows - 1;
            const unsigned short* gp = A + (size_t)gr * Kp + k0 + cbg * 8;
            __builtin_amdgcn_global_load_lds(
                (const __attribute__((address_space(1))) void*)gp,
                (__attribute__((address_space(3))) void*)(&As[q * 8]), 16, 0, 0);
        }
#pragma unroll
        for (int i = 0; i < 4; ++i) {
            int q   = i * 256 + tid;
            int r   = q >> 3;
            int cbg = (q & 7) ^ (r & 7);
            const unsigned short* gp = Bt + (size_t)(nBase + r) * Kp + k0 + cbg * 8;
            __builtin_amdgcn_global_load_lds(
                (const __attribute__((address_space(1))) void*)gp,
                (__attribute__((address_space(3))) void*)(&Bs[q * 8]), 16, 0, 0);
        }
        __syncthreads();
#pragma unroll
        for (int kk = 0; kk < 2; ++kk) {
            bf16x8 a[4], b[4];
            const int cb = kk * 4 + (lane >> 4);
#pragma unroll
            for (int i = 0; i < 4; ++i) {
                int r = wm * 64 + i * 16 + (lane & 15);
                a[i] = *(const bf16x8*)&As[(r * 8 + (cb ^ (r & 7))) * 8];
            }
#pragma unroll
            for (int j = 0; j < 4; ++j) {
                int r = wn * 64 + j * 16 + (lane & 15);
                b[j] = *(const bf16x8*)&Bs[(r * 8 + (cb ^ (r & 7))) * 8];
            }
#pragma unroll
            for (int i = 0; i < 4; ++i)
#pragma unroll
                for (int j = 0; j < 4; ++j)
                    // swapped: weights first -> D cols from regs, rows from lane
                    acc[i][j] = __builtin_amdgcn_mfma_f32_16x16x32_bf16(b[j], a[i], acc[i][j], 0, 0, 0);
        }
    }

    // epilogue (swapped layout): row = ...+(lane&15); col = ...+quad*4+reg
    const int quad = lane >> 4;
#pragma unroll
    for (int i = 0; i < 4; ++i) {
        int row = rowBase + wm * 64 + i * 16 + (lane & 15);
        if (row >= Nrows) continue;
        float sc = 1.f;
        if (DEGB) sc = 1.f + (float)deg[row];
#pragma unroll
        for (int j = 0; j < 4; ++j) {
            int colb = nBase + wn * 64 + j * 16 + quad * 4;
            float4 bv = (colb < Mvalid) ? *(const float4*)(bias + colb)
                                        : (float4){0.f, 0.f, 0.f, 0.f};
            float v0 = acc[i][j][0] + sc * bv.x;
            float v1 = acc[i][j][1] + sc * bv.y;
            float v2 = acc[i][j][2] + sc * bv.z;
            float v3 = acc[i][j][3] + sc * bv.w;
            if (RELU) {
                v0 = v0 > 0.f ? v0 : 0.f; v1 = v1 > 0.f ? v1 : 0.f;
                v2 = v2 > 0.f ? v2 : 0.f; v3 = v3 > 0.f ? v3 : 0.f;
            }
            if (OUT_BF) {
                ushort4 o; o.x = f2bf(v0); o.y = f2bf(v1); o.z = f2bf(v2); o.w = f2bf(v3);
                *(ushort4*)(outB + (size_t)row * Mp + colb) = o;
            }
            if (OUT_F32) {
                if (colb < Mvalid)
                    *(float4*)(outF + (size_t)row * Mvalid + colb) = (float4){v0, v1, v2, v3};
            }
        }
    }
}

// ---------------- CSR build ------------------------------------------------
__global__ void rg_scan_block(const int* __restrict__ cnt, int* __restrict__ scanned,
                              int* __restrict__ bsums, int Nn) {
    __shared__ int sd[1024];
    int tid = threadIdx.x;
    int i = blockIdx.x * 1024 + tid;
    int v = (i < Nn) ? cnt[i] : 0;
    sd[tid] = v;
    __syncthreads();
    for (int off = 1; off < 1024; off <<= 1) {
        int t = (tid >= off) ? sd[tid - off] : 0;
        __syncthreads();
        sd[tid] += t;
        __syncthreads();
    }
    if (i < Nn) scanned[i] = sd[tid];
    if (tid == 1023) bsums[blockIdx.x] = sd[1023];
}

__global__ void rg_scan_sums(int* __restrict__ b, int nb) {
    if (threadIdx.x == 0) {
        int acc = 0;
        for (int i = 0; i < nb; ++i) { int t = b[i]; b[i] = acc; acc += t; }
    }
}

__global__ void rg_scan_add(const int* __restrict__ scanned, const int* __restrict__ bsums,
                            const int* __restrict__ cnt, int* __restrict__ rowptr,
                            int* __restrict__ cursor, int Nn, int E) {
    int i = blockIdx.x * 1024 + threadIdx.x;
    if (i < Nn) {
        int ex = scanned[i] - cnt[i] + bsums[blockIdx.x];
        rowptr[i] = ex; cursor[i] = ex;
    }
    if (i == 0) rowptr[Nn] = E;
}

__global__ void rg_scatter_edges(const int* __restrict__ ei, int E,
                                 int* __restrict__ cursor, int* __restrict__ cols) {
    int e = blockIdx.x * 256 + threadIdx.x;
    if (e < E) {
        int d = ei[E + e];
        int p = atomicAdd(&cursor[d], 1);
        cols[p] = ei[e];
    }
}

// ---------------- 80-dim aggregation: s[i] = pf[i] + sum_{src->i} pf[src] --
// pf is [N,128] bf16 (padded). One wave per node, 2 cols/lane (4B loads).
__global__ __launch_bounds__(256) void rg_agg80(
    const unsigned short* __restrict__ pf, const int* __restrict__ rowptr,
    const int* __restrict__ cols, unsigned short* __restrict__ s, int Nn)
{
    int node = blockIdx.x * 4 + (threadIdx.x >> 6);
    if (node >= Nn) return;
    int lane = threadIdx.x & 63;
    const unsigned* xp = (const unsigned*)pf;   // 64 uints per row
    size_t off = (size_t)node * 64 + lane;
    unsigned u = xp[off];
    float a0 = bf2f(u & 0xffffu), a1 = bf2f(u >> 16);
    int beg = rowptr[node], end = rowptr[node + 1];
    for (int e = beg; e < end; ++e) {
        int src = cols[e];
        unsigned v = xp[(size_t)src * 64 + lane];
        a0 += bf2f(v & 0xffffu); a1 += bf2f(v >> 16);
    }
    unsigned o = (unsigned)f2bf(a0) | ((unsigned)f2bf(a1) << 16);
    ((unsigned*)s)[off] = o;
}

// ---------------------------------------------------------------------------
extern "C" void kernel_launch(void* const* d_in, const int* in_sizes, int n_in,
                              void* d_out, int out_size, void* d_ws, size_t ws_size,
                              hipStream_t stream)
{
    const float* feat = (const float*)d_in[0];
    const int*   ei   = (const int*)d_in[1];
    const float* W1 = (const float*)d_in[2];  const float* b1 = (const float*)d_in[3];
    const float* W2 = (const float*)d_in[4];  const float* b2 = (const float*)d_in[5];
    const float* W3 = (const float*)d_in[6];  const float* b3 = (const float*)d_in[7];
    const float* W4 = (const float*)d_in[8];  const float* b4 = (const float*)d_in[9];
    const float* Wi = (const float*)d_in[10]; const float* bi = (const float*)d_in[11];
    const float* Wg1 = (const float*)d_in[12]; const float* bg1 = (const float*)d_in[13];
    const float* Wg2 = (const float*)d_in[14]; const float* bg2 = (const float*)d_in[15];
    const float* Wo = (const float*)d_in[16]; const float* bo = (const float*)d_in[17];

    const int N = in_sizes[0] / 512;   // 50000
    const int E = in_sizes[1] / 2;     // 800000

    char* ws = (char*)d_ws;
    size_t o = 0;
    auto alloc = [&](size_t bytes) { char* p = ws + o; o += (bytes + 255) & ~(size_t)255; return p; };
    unsigned short* bufA = (unsigned short*)alloc((size_t)N * 1024 * 2); // h1 / pf / g
    unsigned short* bufB = (unsigned short*)alloc((size_t)N * 1024 * 2); // h2 / r1
    unsigned short* bufC = (unsigned short*)alloc((size_t)N * 512 * 2);  // A0 / h3 / s / g2
    unsigned short* W1t = (unsigned short*)alloc((size_t)1024 * 512 * 2);
    unsigned short* W2t = (unsigned short*)alloc((size_t)1024 * 1024 * 2);
    unsigned short* W3t = (unsigned short*)alloc((size_t)512 * 1024 * 2);
    unsigned short* W4t = (unsigned short*)alloc((size_t)128 * 512 * 2);
    unsigned short* Wit = (unsigned short*)alloc((size_t)512 * 128 * 2);
    unsigned short* Wg1t = (unsigned short*)alloc((size_t)512 * 512 * 2);
    unsigned short* Wg2t = (unsigned short*)alloc((size_t)512 * 512 * 2);
    unsigned short* Wot = (unsigned short*)alloc((size_t)128 * 512 * 2);
    int* cnt    = (int*)alloc((size_t)N * 4);
    int* rowptr = (int*)alloc((size_t)(N + 1) * 4);
    int* cursor = (int*)alloc((size_t)N * 4);
    int* cols   = (int*)alloc((size_t)E * 4);   // reused as `scanned` pre-scatter
    int* bsums  = (int*)alloc(256);

    float* out_mask = (float*)d_out;                  // [N,80]
    float* out_feat = (float*)d_out + (size_t)N * 80; // [N,80]

    // ---- merged preprocessing: transposes + feat convert + edge count ----
    hipMemsetAsync(cnt, 0, (size_t)N * 4, stream);
    {
        PreDescs d;
        const float* Ws[8]  = {W1, W2, W3, W4, Wi, Wg1, Wg2, Wo};
        unsigned short* Ts[8] = {W1t, W2t, W3t, W4t, Wit, Wg1t, Wg2t, Wot};
        int Ks[8]  = {512, 1024, 1024, 512, 80, 512, 512, 512};
        int Ms[8]  = {1024, 1024, 512, 80, 512, 512, 512, 80};
        int Kps[8] = {512, 1024, 1024, 512, 128, 512, 512, 512};
        int Mps[8] = {1024, 1024, 512, 128, 512, 512, 512, 128};
        int st = 0;
        for (int i = 0; i < 8; ++i) {
            d.W[i] = Ws[i]; d.Wt[i] = Ts[i];
            d.K[i] = Ks[i]; d.M[i] = Ms[i]; d.Kp[i] = Kps[i];
            d.ntx[i] = Mps[i] / 32;
            d.start[i] = st;
            st += (Mps[i] / 32) * (Kps[i] / 32);
        }
        d.tEnd = st;
        d.cEnd = st + (N * 512) / 1024;
        d.eEnd = d.cEnd + (E + 255) / 256;
        d.feat = feat; d.featb = bufC; d.nFeat = N * 512;
        d.ei = ei; d.E = E; d.cnt = cnt;
        rg_preprocess<<<d.eEnd, 256, 0, stream>>>(d);
    }

    // ---- CSR scan + scatter ----
    int* scanned = cols;  // consumed by rg_scan_add before rg_scatter writes cols
    const int nb = (N + 1023) / 1024;
    rg_scan_block<<<nb, 1024, 0, stream>>>(cnt, scanned, bsums, N);
    rg_scan_sums<<<1, 64, 0, stream>>>(bsums, nb);
    rg_scan_add<<<nb, 1024, 0, stream>>>(scanned, bsums, cnt, rowptr, cursor, N, E);
    rg_scatter_edges<<<(E + 255) / 256, 256, 0, stream>>>(ei, E, cursor, cols);

    const int gN = (N + 127) / 128;          // 391
    const int rg8 = ((gN + 7) / 8) * 8;      // 392
    auto grid = [&](int MT) { return dim3(rg8 * MT); };

    // L1: h1 = relu(A0 @ W1 + b1)   [N,1024]
    rg_gemm<true, true, false, false><<<grid(8), 256, 0, stream>>>(bufC, W1t, b1, nullptr, 1024, bufA, nullptr, N, 512, 1024, gN, 8);
    // L2: h2 = relu(h1 @ W2 + b2)   [N,1024]
    rg_gemm<true, true, false, false><<<grid(8), 256, 0, stream>>>(bufA, W2t, b2, nullptr, 1024, bufB, nullptr, N, 1024, 1024, gN, 8);
    // L3: h3 = relu(h2 @ W3 + b3)   [N,512]
    rg_gemm<true, true, false, false><<<grid(4), 256, 0, stream>>>(bufB, W3t, b3, nullptr, 512, bufC, nullptr, N, 1024, 512, gN, 4);
    // L4: pf = h3 @ W4 + b4  -> fp32 out_feat + bf16 padded [N,128]
    rg_gemm<false, true, true, false><<<grid(1), 256, 0, stream>>>(bufC, W4t, b4, nullptr, 80, bufA, out_feat, N, 512, 128, gN, 1);

    // 80-dim aggregation: s = pf + segsum(pf[src]) -> bufC[:, :128]
    rg_agg80<<<(N + 3) / 4, 256, 0, stream>>>(bufA, rowptr, cols, bufC, N);

    // L5: g = s @ Win + (1+deg)*bin  [N,512]   (agg moved before affine in_net)
    rg_gemm<false, true, false, true><<<grid(4), 256, 0, stream>>>(bufC, Wit, bi, cnt, 512, bufA, nullptr, N, 128, 512, gN, 4);
    // L6: r1 = relu(g @ Wg1 + bg1)  [N,512]
    rg_gemm<true, true, false, false><<<grid(4), 256, 0, stream>>>(bufA, Wg1t, bg1, nullptr, 512, bufB, nullptr, N, 512, 512, gN, 4);
    // L7: g2 = r1 @ Wg2 + bg2       [N,512]
    rg_gemm<false, true, false, false><<<grid(4), 256, 0, stream>>>(bufB, Wg2t, bg2, nullptr, 512, bufC, nullptr, N, 512, 512, gN, 4);
    // L8: mask = g2 @ Wout + bout -> fp32 out_mask
    rg_gemm<false, false, true, false><<<grid(1), 256, 0, stream>>>(bufC, Wot, bo, nullptr, 80, nullptr, out_mask, N, 512, 128, gN, 1);
}

// Round 5
// 816.036 us; speedup vs baseline: 1.1377x; 1.0374x over previous
//
#include <hip/hip_runtime.h>
#include <stdint.h>

// ---------------------------------------------------------------------------
// ResidueGraphModel: aanet_proj (512->1024->1024->512->80, ReLU) -> in_net
// (80->512) -> GIN sum-aggregation + MLP (512->512->512) -> out_net (512->80).
// bf16 MFMA GEMMs (fp32 accumulate), 128x128 tiles, BK=64, 16x16x32 MFMA.
// R5: agg80 edge-loop unrolled x8 (8 outstanding gathers vs serialized
// dependent chain), scan_sums as 64-lane shfl wave scan (was 1 thread x 49
// dependent global round-trips), activation buffers row-padded to 50048 so
// the GEMM A-load row clamp is gone, MT templatized (no runtime div in
// block decode). GEMM core otherwise identical to R4 (0 bank conflicts,
// packed 8B C stores, XCD-grouped decode, agg before in_net).
// Outputs fp32: d_out = [peptide_mask (N*80) | peptide_feat (N*80)].
// ---------------------------------------------------------------------------

using bf16x8 = __attribute__((ext_vector_type(8))) short;
using f32x4  = __attribute__((ext_vector_type(4))) float;

__device__ inline unsigned short f2bf(float f) {
    union { float f; unsigned u; } v; v.f = f;
    unsigned u = v.u;
    u += 0x7FFFu + ((u >> 16) & 1u);   // RNE
    return (unsigned short)(u >> 16);
}
__device__ inline float bf2f(unsigned u16) {
    return __uint_as_float(u16 << 16);
}

// ------------- merged preprocessing ----------------------------------------
// Block ranges: [0, tEnd) -> weight transpose+convert (32x32 tiles, 256 thr)
//               [tEnd, cEnd) -> feat f32->bf16 convert (1024 elems/block)
//               [cEnd, eEnd) -> edge dst counting (256 edges/block)
struct PreDescs {
    const float* W[8]; unsigned short* Wt[8];
    int K[8], M[8], Kp[8], ntx[8], start[8];
    int tEnd, cEnd, eEnd;
    const float* feat; unsigned short* featb; int nFeat;
    const int* ei; int E; int* cnt;
};

__global__ __launch_bounds__(256) void rg_preprocess(PreDescs d) {
    int b = blockIdx.x;
    int tid = threadIdx.x;
    if (b < d.tEnd) {
        // transpose: W[K][M] f32 -> Wt[Mp][Kp] bf16 (pad with 0)
        __shared__ float t[32][33];
        int di = 0;
#pragma unroll
        for (int i = 1; i < 8; ++i) if (b >= d.start[i]) di = i;
        int local = b - d.start[di];
        int bx = local % d.ntx[di];
        int by = local / d.ntx[di];
        const float* W = d.W[di];
        unsigned short* Wt = d.Wt[di];
        int K = d.K[di], M = d.M[di], Kp = d.Kp[di];
        int mb = bx * 32, kb = by * 32;
        int tx = tid & 31, tg = tid >> 5;   // 8 rows per pass, 4 passes
#pragma unroll
        for (int p = 0; p < 4; ++p) {
            int r = tg + p * 8;             // tile row (k-dir)
            int k = kb + r, m = mb + tx;
            t[r][tx] = (k < K && m < M) ? W[(size_t)k * M + m] : 0.f;
        }
        __syncthreads();
#pragma unroll
        for (int p = 0; p < 4; ++p) {
            int r = tg + p * 8;             // tile row (m-dir)
            int mo = mb + r, ko = kb + tx;
            Wt[(size_t)mo * Kp + ko] = f2bf(t[tx][r]);
        }
    } else if (b < d.cEnd) {
        int i = ((b - d.tEnd) * 256 + tid) * 4;
        if (i + 3 < d.nFeat) {
            float4 v = *(const float4*)(d.feat + i);
            ushort4 o; o.x = f2bf(v.x); o.y = f2bf(v.y); o.z = f2bf(v.z); o.w = f2bf(v.w);
            *(ushort4*)(d.featb + i) = o;
        }
    } else {
        int e = (b - d.cEnd) * 256 + tid;
        if (e < d.E) atomicAdd(&d.cnt[d.ei[d.E + e]], 1);
    }
}

// ---------------- GEMM: C[N,Mp] = act(A[N,Kp] @ Wt[Mp,Kp]^T + bscale*bias) --
// XOR swizzle: LDS chunk q (16B) of a tile row r holds global chunk
// (q&7)^(r&7); staging lane loads the matching global address, fragment
// reads apply the same XOR -> zero measured bank conflicts.
// Operand swap: weights as first MFMA operand -> acc regs hold 4 consecutive
// output columns -> 8B packed stores (32B/row per store instruction).
// A buffers are row-padded to Npad: no row clamp on staging loads; pad rows
// stage garbage whose acc results are masked at the store (row < Nrows).
template <bool RELU, bool OUT_BF, bool OUT_F32, bool DEGB, int MT>
__global__ __launch_bounds__(256) void rg_gemm(
    const unsigned short* __restrict__ A, const unsigned short* __restrict__ Bt,
    const float* __restrict__ bias, const int* __restrict__ deg, int Mvalid,
    unsigned short* __restrict__ outB, float* __restrict__ outF,
    int Nrows, int Kp, int Mp, int gN)
{
    __shared__ __align__(16) unsigned short As[128 * 64];
    __shared__ __align__(16) unsigned short Bs[128 * 64];

    // XCD-grouped decode: a row strip's MT col-blocks share (bid&7), 8 apart
    // in issue order -> A strip stays hot in L2/L3 across column passes.
    int bid = blockIdx.x;
    int xcd = bid & 7;
    int slot = bid >> 3;
    int c = slot % MT;
    int rsub = slot / MT;
    int rt = rsub * 8 + xcd;
    if (rt >= gN) return;
    const int rowBase = rt * 128;
    const int nBase   = c * 128;

    const int tid  = threadIdx.x;
    const int lane = tid & 63;
    const int w    = tid >> 6;
    const int wm   = w & 1, wn = w >> 1;

    f32x4 acc[4][4];
#pragma unroll
    for (int i = 0; i < 4; ++i)
#pragma unroll
        for (int j = 0; j < 4; ++j) acc[i][j] = (f32x4){0.f, 0.f, 0.f, 0.f};

    const int nkt = Kp >> 6;
    for (int kt = 0; kt < nkt; ++kt) {
        __syncthreads();
        const int k0 = kt * 64;
#pragma unroll
        for (int i = 0; i < 4; ++i) {
            int q   = i * 256 + tid;       // LDS 16B-chunk slot
            int r   = q >> 3;
            int cbg = (q & 7) ^ (r & 7);   // global chunk staged into slot q
            const unsigned short* gp = A + (size_t)(rowBase + r) * Kp + k0 + cbg * 8;
            __builtin_amdgcn_global_load_lds(
                (const __attribute__((address_space(1))) void*)gp,
                (__attribute__((address_space(3))) void*)(&As[q * 8]), 16, 0, 0);
        }
#pragma unroll
        for (int i = 0; i < 4; ++i) {
            int q   = i * 256 + tid;
            int r   = q >> 3;
            int cbg = (q & 7) ^ (r & 7);
            const unsigned short* gp = Bt + (size_t)(nBase + r) * Kp + k0 + cbg * 8;
            __builtin_amdgcn_global_load_lds(
                (const __attribute__((address_space(1))) void*)gp,
                (__attribute__((address_space(3))) void*)(&Bs[q * 8]), 16, 0, 0);
        }
        __syncthreads();
#pragma unroll
        for (int kk = 0; kk < 2; ++kk) {
            bf16x8 a[4], b[4];
            const int cb = kk * 4 + (lane >> 4);
#pragma unroll
            for (int i = 0; i < 4; ++i) {
                int r = wm * 64 + i * 16 + (lane & 15);
                a[i] = *(const bf16x8*)&As[(r * 8 + (cb ^ (r & 7))) * 8];
            }
#pragma unroll
            for (int j = 0; j < 4; ++j) {
                int r = wn * 64 + j * 16 + (lane & 15);
                b[j] = *(const bf16x8*)&Bs[(r * 8 + (cb ^ (r & 7))) * 8];
            }
#pragma unroll
            for (int i = 0; i < 4; ++i)
#pragma unroll
                for (int j = 0; j < 4; ++j)
                    // swapped: weights first -> D cols from regs, rows from lane
                    acc[i][j] = __builtin_amdgcn_mfma_f32_16x16x32_bf16(b[j], a[i], acc[i][j], 0, 0, 0);
        }
    }

    // epilogue (swapped layout): row = ...+(lane&15); col = ...+quad*4+reg
    const int quad = lane >> 4;
#pragma unroll
    for (int i = 0; i < 4; ++i) {
        int row = rowBase + wm * 64 + i * 16 + (lane & 15);
        if (row >= Nrows) continue;
        float sc = 1.f;
        if (DEGB) sc = 1.f + (float)deg[row];
#pragma unroll
        for (int j = 0; j < 4; ++j) {
            int colb = nBase + wn * 64 + j * 16 + quad * 4;
            float4 bv = (colb < Mvalid) ? *(const float4*)(bias + colb)
                                        : (float4){0.f, 0.f, 0.f, 0.f};
            float v0 = acc[i][j][0] + sc * bv.x;
            float v1 = acc[i][j][1] + sc * bv.y;
            float v2 = acc[i][j][2] + sc * bv.z;
            float v3 = acc[i][j][3] + sc * bv.w;
            if (RELU) {
                v0 = v0 > 0.f ? v0 : 0.f; v1 = v1 > 0.f ? v1 : 0.f;
                v2 = v2 > 0.f ? v2 : 0.f; v3 = v3 > 0.f ? v3 : 0.f;
            }
            if (OUT_BF) {
                ushort4 o; o.x = f2bf(v0); o.y = f2bf(v1); o.z = f2bf(v2); o.w = f2bf(v3);
                *(ushort4*)(outB + (size_t)row * Mp + colb) = o;
            }
            if (OUT_F32) {
                if (colb < Mvalid)
                    *(float4*)(outF + (size_t)row * Mvalid + colb) = (float4){v0, v1, v2, v3};
            }
        }
    }
}

// ---------------- CSR build ------------------------------------------------
__global__ void rg_scan_block(const int* __restrict__ cnt, int* __restrict__ scanned,
                              int* __restrict__ bsums, int Nn) {
    __shared__ int sd[1024];
    int tid = threadIdx.x;
    int i = blockIdx.x * 1024 + tid;
    int v = (i < Nn) ? cnt[i] : 0;
    sd[tid] = v;
    __syncthreads();
    for (int off = 1; off < 1024; off <<= 1) {
        int t = (tid >= off) ? sd[tid - off] : 0;
        __syncthreads();
        sd[tid] += t;
        __syncthreads();
    }
    if (i < Nn) scanned[i] = sd[tid];
    if (tid == 1023) bsums[blockIdx.x] = sd[1023];
}

// exclusive scan of block sums: 64-lane shfl wave scan with carry loop
__global__ void rg_scan_sums(int* __restrict__ b, int nb) {
    int tid = threadIdx.x;   // 64 threads
    int carry = 0;
    for (int base = 0; base < nb; base += 64) {
        int i = base + tid;
        int v = (i < nb) ? b[i] : 0;
        int incl = v;
#pragma unroll
        for (int off = 1; off < 64; off <<= 1) {
            int t = __shfl_up(incl, off, 64);
            if (tid >= off) incl += t;
        }
        if (i < nb) b[i] = carry + incl - v;
        carry += __shfl(incl, 63, 64);
    }
}

__global__ void rg_scan_add(const int* __restrict__ scanned, const int* __restrict__ bsums,
                            const int* __restrict__ cnt, int* __restrict__ rowptr,
                            int* __restrict__ cursor, int Nn, int E) {
    int i = blockIdx.x * 1024 + threadIdx.x;
    if (i < Nn) {
        int ex = scanned[i] - cnt[i] + bsums[blockIdx.x];
        rowptr[i] = ex; cursor[i] = ex;
    }
    if (i == 0) rowptr[Nn] = E;
}

__global__ void rg_scatter_edges(const int* __restrict__ ei, int E,
                                 int* __restrict__ cursor, int* __restrict__ cols) {
    int e = blockIdx.x * 256 + threadIdx.x;
    if (e < E) {
        int d = ei[E + e];
        int p = atomicAdd(&cursor[d], 1);
        cols[p] = ei[e];
    }
}

// ---------------- 80-dim aggregation: s[i] = pf[i] + sum_{src->i} pf[src] --
// pf is [Npad,128] bf16. One wave per node, 1 uint (2 cols) per lane.
// Edge loop unrolled x8: 8 independent outstanding gathers per iteration
// (the serial load->add chain was the R4 bottleneck here).
__global__ __launch_bounds__(256) void rg_agg80(
    const unsigned short* __restrict__ pf, const int* __restrict__ rowptr,
    const int* __restrict__ cols, unsigned short* __restrict__ s, int Nn)
{
    int node = blockIdx.x * 4 + (threadIdx.x >> 6);
    if (node >= Nn) return;
    int lane = threadIdx.x & 63;
    const unsigned* xp = (const unsigned*)pf;   // 64 uints per row
    size_t off = (size_t)node * 64 + lane;
    unsigned u = xp[off];
    float a0 = bf2f(u & 0xffffu), a1 = bf2f(u >> 16);
    int beg = rowptr[node], end = rowptr[node + 1];
    int e = beg;
    for (; e + 8 <= end; e += 8) {
        unsigned v[8];
#pragma unroll
        for (int t = 0; t < 8; ++t) v[t] = xp[(size_t)cols[e + t] * 64 + lane];
#pragma unroll
        for (int t = 0; t < 8; ++t) { a0 += bf2f(v[t] & 0xffffu); a1 += bf2f(v[t] >> 16); }
    }
    for (; e < end; ++e) {
        unsigned v = xp[(size_t)cols[e] * 64 + lane];
        a0 += bf2f(v & 0xffffu); a1 += bf2f(v >> 16);
    }
    unsigned o = (unsigned)f2bf(a0) | ((unsigned)f2bf(a1) << 16);
    ((unsigned*)s)[off] = o;
}

// ---------------------------------------------------------------------------
extern "C" void kernel_launch(void* const* d_in, const int* in_sizes, int n_in,
                              void* d_out, int out_size, void* d_ws, size_t ws_size,
                              hipStream_t stream)
{
    const float* feat = (const float*)d_in[0];
    const int*   ei   = (const int*)d_in[1];
    const float* W1 = (const float*)d_in[2];  const float* b1 = (const float*)d_in[3];
    const float* W2 = (const float*)d_in[4];  const float* b2 = (const float*)d_in[5];
    const float* W3 = (const float*)d_in[6];  const float* b3 = (const float*)d_in[7];
    const float* W4 = (const float*)d_in[8];  const float* b4 = (const float*)d_in[9];
    const float* Wi = (const float*)d_in[10]; const float* bi = (const float*)d_in[11];
    const float* Wg1 = (const float*)d_in[12]; const float* bg1 = (const float*)d_in[13];
    const float* Wg2 = (const float*)d_in[14]; const float* bg2 = (const float*)d_in[15];
    const float* Wo = (const float*)d_in[16]; const float* bo = (const float*)d_in[17];

    const int N = in_sizes[0] / 512;   // 50000
    const int E = in_sizes[1] / 2;     // 800000
    const int gN = (N + 127) / 128;    // 391
    const int Npad = gN * 128;         // 50048: GEMM A-loads never clamp

    char* ws = (char*)d_ws;
    size_t o = 0;
    auto alloc = [&](size_t bytes) { char* p = ws + o; o += (bytes + 255) & ~(size_t)255; return p; };
    unsigned short* bufA = (unsigned short*)alloc((size_t)Npad * 1024 * 2); // h1 / pf / g
    unsigned short* bufB = (unsigned short*)alloc((size_t)Npad * 1024 * 2); // h2 / r1
    unsigned short* bufC = (unsigned short*)alloc((size_t)Npad * 512 * 2);  // A0 / h3 / s / g2
    unsigned short* W1t = (unsigned short*)alloc((size_t)1024 * 512 * 2);
    unsigned short* W2t = (unsigned short*)alloc((size_t)1024 * 1024 * 2);
    unsigned short* W3t = (unsigned short*)alloc((size_t)512 * 1024 * 2);
    unsigned short* W4t = (unsigned short*)alloc((size_t)128 * 512 * 2);
    unsigned short* Wit = (unsigned short*)alloc((size_t)512 * 128 * 2);
    unsigned short* Wg1t = (unsigned short*)alloc((size_t)512 * 512 * 2);
    unsigned short* Wg2t = (unsigned short*)alloc((size_t)512 * 512 * 2);
    unsigned short* Wot = (unsigned short*)alloc((size_t)128 * 512 * 2);
    int* cnt    = (int*)alloc((size_t)N * 4);
    int* rowptr = (int*)alloc((size_t)(N + 1) * 4);
    int* cursor = (int*)alloc((size_t)N * 4);
    int* cols   = (int*)alloc((size_t)E * 4);   // reused as `scanned` pre-scatter
    int* bsums  = (int*)alloc(256);

    float* out_mask = (float*)d_out;                  // [N,80]
    float* out_feat = (float*)d_out + (size_t)N * 80; // [N,80]

    // ---- merged preprocessing: transposes + feat convert + edge count ----
    hipMemsetAsync(cnt, 0, (size_t)N * 4, stream);
    {
        PreDescs d;
        const float* Ws[8]  = {W1, W2, W3, W4, Wi, Wg1, Wg2, Wo};
        unsigned short* Ts[8] = {W1t, W2t, W3t, W4t, Wit, Wg1t, Wg2t, Wot};
        int Ks[8]  = {512, 1024, 1024, 512, 80, 512, 512, 512};
        int Ms[8]  = {1024, 1024, 512, 80, 512, 512, 512, 80};
        int Kps[8] = {512, 1024, 1024, 512, 128, 512, 512, 512};
        int Mps[8] = {1024, 1024, 512, 128, 512, 512, 512, 128};
        int st = 0;
        for (int i = 0; i < 8; ++i) {
            d.W[i] = Ws[i]; d.Wt[i] = Ts[i];
            d.K[i] = Ks[i]; d.M[i] = Ms[i]; d.Kp[i] = Kps[i];
            d.ntx[i] = Mps[i] / 32;
            d.start[i] = st;
            st += (Mps[i] / 32) * (Kps[i] / 32);
        }
        d.tEnd = st;
        d.cEnd = st + (N * 512) / 1024;
        d.eEnd = d.cEnd + (E + 255) / 256;
        d.feat = feat; d.featb = bufC; d.nFeat = N * 512;
        d.ei = ei; d.E = E; d.cnt = cnt;
        rg_preprocess<<<d.eEnd, 256, 0, stream>>>(d);
    }

    // ---- CSR scan + scatter ----
    int* scanned = cols;  // consumed by rg_scan_add before rg_scatter writes cols
    const int nb = (N + 1023) / 1024;
    rg_scan_block<<<nb, 1024, 0, stream>>>(cnt, scanned, bsums, N);
    rg_scan_sums<<<1, 64, 0, stream>>>(bsums, nb);
    rg_scan_add<<<nb, 1024, 0, stream>>>(scanned, bsums, cnt, rowptr, cursor, N, E);
    rg_scatter_edges<<<(E + 255) / 256, 256, 0, stream>>>(ei, E, cursor, cols);

    const int rg8 = ((gN + 7) / 8) * 8;      // 392
    auto grid = [&](int MT) { return dim3(rg8 * MT); };

    // L1: h1 = relu(A0 @ W1 + b1)   [N,1024]
    rg_gemm<true, true, false, false, 8><<<grid(8), 256, 0, stream>>>(bufC, W1t, b1, nullptr, 1024, bufA, nullptr, N, 512, 1024, gN);
    // L2: h2 = relu(h1 @ W2 + b2)   [N,1024]
    rg_gemm<true, true, false, false, 8><<<grid(8), 256, 0, stream>>>(bufA, W2t, b2, nullptr, 1024, bufB, nullptr, N, 1024, 1024, gN);
    // L3: h3 = relu(h2 @ W3 + b3)   [N,512]
    rg_gemm<true, true, false, false, 4><<<grid(4), 256, 0, stream>>>(bufB, W3t, b3, nullptr, 512, bufC, nullptr, N, 1024, 512, gN);
    // L4: pf = h3 @ W4 + b4  -> fp32 out_feat + bf16 padded [N,128]
    rg_gemm<false, true, true, false, 1><<<grid(1), 256, 0, stream>>>(bufC, W4t, b4, nullptr, 80, bufA, out_feat, N, 512, 128, gN);

    // 80-dim aggregation: s = pf + segsum(pf[src]) -> bufC[:, :128]
    rg_agg80<<<(N + 3) / 4, 256, 0, stream>>>(bufA, rowptr, cols, bufC, N);

    // L5: g = s @ Win + (1+deg)*bin  [N,512]   (agg moved before affine in_net)
    rg_gemm<false, true, false, true, 4><<<grid(4), 256, 0, stream>>>(bufC, Wit, bi, cnt, 512, bufA, nullptr, N, 128, 512, gN);
    // L6: r1 = relu(g @ Wg1 + bg1)  [N,512]
    rg_gemm<true, true, false, false, 4><<<grid(4), 256, 0, stream>>>(bufA, Wg1t, bg1, nullptr, 512, bufB, nullptr, N, 512, 512, gN);
    // L7: g2 = r1 @ Wg2 + bg2       [N,512]
    rg_gemm<false, true, false, false, 4><<<grid(4), 256, 0, stream>>>(bufB, Wg2t, bg2, nullptr, 512, bufC, nullptr, N, 512, 512, gN);
    // L8: mask = g2 @ Wout + bout -> fp32 out_mask
    rg_gemm<false, false, true, false, 1><<<grid(1), 256, 0, stream>>>(bufC, Wot, bo, nullptr, 80, nullptr, out_mask, N, 512, 128, gN);
}